// Round 1
// baseline (154.819 us; speedup 1.0000x reference)
//
#include <hip/hip_runtime.h>
#include <cstdint>
#include <cstddef>

// Problem constants
#define B_DIM 4096   // batch (GEMM M)
#define S_DIM 2048   // states (GEMM N)
#define D_DIM 2496   // feature dim (GEMM K) = 78 * 32

// GEMM tiling (m97 structure: 128x128 tile, BK=32, 4 waves of 4x4 16x16x32 MFMA)
#define BM 128
#define BN 128
#define BK 32

typedef __attribute__((ext_vector_type(8))) short short8;
typedef __attribute__((ext_vector_type(4))) float f32x4;

// ---------------------------------------------------------------------------
// fp32 -> bf16 round-to-nearest-even (inputs are positive uniforms; no NaN)
__device__ __forceinline__ unsigned short f2bf(float f) {
    union { float f; unsigned int u; } v; v.f = f;
    unsigned int r = (v.u + 0x7fffu + ((v.u >> 16) & 1u)) >> 16;
    return (unsigned short)r;
}

struct __attribute__((aligned(8))) us4 { unsigned short x, y, z, w; };

// ---------------------------------------------------------------------------
// Prep: convert one row (of X for blk<B_DIM, else of M) to bf16 and compute
// its fp32 squared norm. Memory-bound: ~92 MB total traffic.
__global__ __launch_bounds__(256) void prep_kernel(
    const float* __restrict__ X, const float* __restrict__ Mx,
    unsigned short* __restrict__ Xb, unsigned short* __restrict__ Mb,
    float* __restrict__ xsq, float* __restrict__ msq)
{
    const int blk = blockIdx.x;
    const float* src; unsigned short* dst; float* sq;
    if (blk < B_DIM) {
        src = X + (size_t)blk * D_DIM; dst = Xb + (size_t)blk * D_DIM; sq = xsq + blk;
    } else {
        const int r = blk - B_DIM;
        src = Mx + (size_t)r * D_DIM; dst = Mb + (size_t)r * D_DIM; sq = msq + r;
    }
    const float4* s4 = (const float4*)src;
    us4* d4 = (us4*)dst;
    float acc = 0.f;
    for (int i = threadIdx.x; i < D_DIM / 4; i += 256) {
        float4 v = s4[i];
        acc += v.x * v.x + v.y * v.y + v.z * v.z + v.w * v.w;
        us4 h; h.x = f2bf(v.x); h.y = f2bf(v.y); h.z = f2bf(v.z); h.w = f2bf(v.w);
        d4[i] = h;
    }
    // wave64 shuffle reduce, then 4-wave LDS reduce
    #pragma unroll
    for (int off = 32; off > 0; off >>= 1)
        acc += __shfl_down(acc, off, 64);
    __shared__ float red[4];
    const int lane = threadIdx.x & 63, wave = threadIdx.x >> 6;
    if (lane == 0) red[wave] = acc;
    __syncthreads();
    if (threadIdx.x == 0) *sq = red[0] + red[1] + red[2] + red[3];
}

// ---------------------------------------------------------------------------
// global -> LDS direct (async) load, 16 B per lane. LDS dest is wave-uniform
// base + lane*16 (hardware-defined scatter) — LDS layout must be contiguous
// in lane order, so no padding on the BK dimension.
__device__ __forceinline__ void gld_lds16(const unsigned short* g, unsigned short* l) {
    __builtin_amdgcn_global_load_lds(
        (const __attribute__((address_space(1))) unsigned int*)g,
        (__attribute__((address_space(3))) unsigned int*)l,
        16, 0, 0);
}

// ---------------------------------------------------------------------------
// C[row,col] = (2*sum_k A[row,k]*B[col,k] - xsq[row] - msq[col]) / 500
// A: [4096, 2496] bf16 row-major; Bt: [2048, 2496] bf16 row-major (NT GEMM).
__global__ __launch_bounds__(256) void gemm_kernel(
    const unsigned short* __restrict__ A,
    const unsigned short* __restrict__ Bt,
    const float* __restrict__ xsq, const float* __restrict__ msq,
    float* __restrict__ C)
{
    constexpr int N = S_DIM;
    constexpr int K = D_DIM;

    __shared__ __align__(16) unsigned short As[BM * BK];  // 8 KB
    __shared__ __align__(16) unsigned short Bs[BN * BK];  // 8 KB

    const int tid  = threadIdx.x;
    const int lane = tid & 63;
    const int wave = tid >> 6;       // 4 waves
    const int wm = wave >> 1;        // wave row (0..1) -> 64 rows
    const int wn = wave & 1;         // wave col (0..1) -> 64 cols
    const int bm = blockIdx.y;
    const int bn = blockIdx.x;

    // Staging: each wave issues 2 gld_lds16 per matrix; one issue covers
    // 16 rows x 32 cols bf16 (64 lanes x 16 B). Lane i -> row srow, 8-elem
    // k-segment skk; LDS lands at base + lane*16 which equals row*64+seg*16.
    const int srow = wave * 32 + (lane >> 2);
    const int skk  = (lane & 3) * 8;
    const unsigned short* gA = A  + (size_t)(bm * BM + srow) * K + skk;
    const unsigned short* gB = Bt + (size_t)(bn * BN + srow) * K + skk;
    unsigned short* lA0 = &As[(wave * 32     ) * BK];
    unsigned short* lA1 = &As[(wave * 32 + 16) * BK];
    unsigned short* lB0 = &Bs[(wave * 32     ) * BK];
    unsigned short* lB1 = &Bs[(wave * 32 + 16) * BK];

    f32x4 acc[4][4] = {};

    const int ko = (lane >> 4) * 8;  // A/B frag: k = quad*8 + j
    const int fr = lane & 15;        // A/B frag: m (or n) = lane & 15

    for (int k0 = 0; k0 < K; k0 += BK) {
        __syncthreads();   // previous tile fully consumed
        gld_lds16(gA,                 lA0);
        gld_lds16(gA + (size_t)16 * K, lA1);
        gld_lds16(gB,                 lB0);
        gld_lds16(gB + (size_t)16 * K, lB1);
        gA += BK; gB += BK;
        __syncthreads();   // compiler drains vmcnt(0) before barrier

        short8 af[4], bfr[4];
        #pragma unroll
        for (int i = 0; i < 4; ++i) {
            af[i]  = *(const short8*)&As[(wm * 64 + i * 16 + fr) * BK + ko];
            bfr[i] = *(const short8*)&Bs[(wn * 64 + i * 16 + fr) * BK + ko];
        }
        #pragma unroll
        for (int mi = 0; mi < 4; ++mi)
            #pragma unroll
            for (int ni = 0; ni < 4; ++ni)
                acc[mi][ni] = __builtin_amdgcn_mfma_f32_16x16x32_bf16(
                    af[mi], bfr[ni], acc[mi][ni], 0, 0, 0);
    }

    // Epilogue. C/D layout: col = lane&15, row = (lane>>4)*4 + reg (m89/m91).
    const int row0 = bm * BM + wm * 64 + (lane >> 4) * 4;
    const int col0 = bn * BN + wn * 64 + fr;
    float ms[4];
    #pragma unroll
    for (int ni = 0; ni < 4; ++ni) ms[ni] = msq[col0 + ni * 16];
    #pragma unroll
    for (int mi = 0; mi < 4; ++mi) {
        #pragma unroll
        for (int r = 0; r < 4; ++r) {
            const int row = row0 + mi * 16 + r;
            const float xs = xsq[row];
            #pragma unroll
            for (int ni = 0; ni < 4; ++ni) {
                const float v = (2.0f * acc[mi][ni][r] - xs - ms[ni]) * (1.0f / 500.0f);
                C[(size_t)row * N + col0 + ni * 16] = v;
            }
        }
    }
}

// ---------------------------------------------------------------------------
extern "C" void kernel_launch(void* const* d_in, const int* in_sizes, int n_in,
                              void* d_out, int out_size, void* d_ws, size_t ws_size,
                              hipStream_t stream) {
    const float* X  = (const float*)d_in[0];  // [4096, 2496]
    const float* Mx = (const float*)d_in[1];  // [2048, 2496]
    float* out = (float*)d_out;               // [4096, 2048]

    // Workspace layout (~30.7 MB): Xb bf16 | Mb bf16 | xsq f32 | msq f32
    unsigned short* Xb = (unsigned short*)d_ws;
    unsigned short* Mb = Xb + (size_t)B_DIM * D_DIM;
    float* xsq = (float*)(Mb + (size_t)S_DIM * D_DIM);
    float* msq = xsq + B_DIM;

    prep_kernel<<<B_DIM + S_DIM, 256, 0, stream>>>(X, Mx, Xb, Mb, xsq, msq);

    dim3 grid(S_DIM / BN, B_DIM / BM);  // (16, 32) = 512 blocks -> 2/CU
    gemm_kernel<<<grid, 256, 0, stream>>>(Xb, Mb, xsq, msq, out);
}